// Round 5
// baseline (141.020 us; speedup 1.0000x reference)
//
#include <hip/hip_runtime.h>

#define KK 121                   // 11*11
#define NPAIR (512 * 512)        // 262,144 (o,i) pairs
#define PPB 64                   // pairs per chunk
#define NCHUNK (NPAIR / PPB)     // 4096 chunks
#define GRID 512                 // persistent blocks, 2 per CU (LDS-bound)
#define CPB (NCHUNK / GRID)      // 8 chunks per block (exact)
#define STAGE_F4 (PPB * KK / 4)  // 1936 float4 per chunk (exact)

typedef float vf4 __attribute__((ext_vector_type(4)));  // native vec: builtin-compatible

// out[p][k] = P_p*u[k] + Q_p*v[k] + R_p*w[k], u=x1^2 v=x2^2 w=x1*x2
//   e1 = exp(-a00), e2 = exp(-a11), f = a10*e2
//   P = e1^2*(1+f^2), Q = e2^2, R = -2*f*e1*e2
__global__ __launch_bounds__(256) void
quad_persist_kernel(const vf4* __restrict__ chol4,
                    const float* __restrict__ pg,
                    vf4* __restrict__ out4) {
    __shared__ vf4 s_uvw[KK];                           // 1,936 B
    __shared__ __align__(16) float stage[2][PPB * KK];  // 2 x 30,976 B

    const int t = threadIdx.x;

    if (t < KK) {
        float x1 = pg[t];
        float x2 = pg[KK + t];
        vf4 g;
        g.x = x1 * x1; g.y = x2 * x2; g.z = x1 * x2; g.w = 0.f;
        s_uvw[t] = g;
    }

    const int p       = t & 63;      // pair within chunk
    const int quarter = t >> 6;      // wave id: k-ranges 31,30,30,30
    const int k0 = (quarter == 0) ? 0 : (30 * quarter + 1);
    const int k1 = (quarter == 0) ? 31 : (k0 + 30);

    __syncthreads();                 // s_uvw ready

    for (int c = 0; c < CPB; ++c) {
        const int chunk = blockIdx.x * CPB + c;   // linear 248 KB region/block

        // per-pair params (4 threads/pair duplicate this)
        vf4 cc = chol4[chunk * PPB + p];          // {a00,a01,a10,a11}
        float e1 = __expf(-cc.x);
        float e2 = __expf(-cc.w);
        float f  = cc.z * e2;
        float P  = e1 * e1 * fmaf(f, f, 1.f);
        float Q  = e2 * e2;
        float R  = -2.f * f * e1 * e2;

        float* st = &stage[c & 1][p * KK];        // bank stride 25: 2-way, free
#pragma unroll 5
        for (int k = k0; k < k1; ++k) {
            vf4 g = s_uvw[k];                     // broadcast read
            st[k] = fmaf(P, g.x, fmaf(Q, g.y, R * g.z));
        }

        // Single barrier per chunk, BETWEEN compute and store. Double buffer:
        // chunk c+2 reuses buffer (c&1); barrier of chunk c+1 has already
        // drained every thread's ds_reads of chunk c's store loop. No
        // post-store barrier -> stores stay in flight across chunks.
        __syncthreads();

        const vf4* s4 = (const vf4*)stage[c & 1];
        vf4* o = out4 + (size_t)chunk * STAGE_F4;
#pragma unroll
        for (int i = t; i < STAGE_F4; i += 256) {
            __builtin_nontemporal_store(s4[i], &o[i]);  // bypass cache alloc
        }
    }
}

extern "C" void kernel_launch(void* const* d_in, const int* in_sizes, int n_in,
                              void* d_out, int out_size, void* d_ws, size_t ws_size,
                              hipStream_t stream) {
    const vf4* chol4 = (const vf4*)d_in[0];   // (512,512,2,2) fp32
    const float* pg  = (const float*)d_in[1]; // (2,121) fp32
    vf4* out4        = (vf4*)d_out;           // (512,512,11,11) fp32

    quad_persist_kernel<<<GRID, 256, 0, stream>>>(chol4, pg, out4);
}

// Round 6
// 137.336 us; speedup vs baseline: 1.0268x; 1.0268x over previous
//
#include <hip/hip_runtime.h>

#define KK 121                   // 11*11
#define NPAIR (512 * 512)        // 262,144 (o,i) pairs
#define PPB 64                   // pairs per block
#define NBLK (NPAIR / PPB)       // 4096 blocks
#define STAGE_F4 (PPB * KK / 4)  // 1936 float4 per block (exact)

typedef float vf4 __attribute__((ext_vector_type(4)));

// out[p][k] = P_p*u[k] + Q_p*v[k] + R_p*w[k], u=x1^2 v=x2^2 w=x1*x2
//   e1 = exp(-a00), e2 = exp(-a11), f = a10*e2
//   P = e1^2*(1+f^2), Q = e2^2, R = -2*f*e1*e2
__global__ __launch_bounds__(256) void
quad_rank3_nt_kernel(const vf4* __restrict__ chol4,
                     const float* __restrict__ pg,
                     vf4* __restrict__ out4) {
    __shared__ vf4 s_uvw[KK];                       // {x1^2, x2^2, x1*x2, 0}
    __shared__ __align__(16) float stage[PPB * KK]; // 30,976 B

    const int t = threadIdx.x;

    if (t < KK) {
        float x1 = pg[t];
        float x2 = pg[KK + t];
        vf4 g;
        g.x = x1 * x1; g.y = x2 * x2; g.z = x1 * x2; g.w = 0.f;
        s_uvw[t] = g;
    }

    const int p       = t & 63;         // pair within block
    const int quarter = t >> 6;         // 0..3 -> kp ranges 31,30,30,30
    const int k0 = (quarter == 0) ? 0 : (30 * quarter + 1);
    const int k1 = (quarter == 0) ? 31 : (k0 + 30);

    // per-pair params (4 threads/pair duplicate this tiny bit of work)
    vf4 c = chol4[blockIdx.x * PPB + p];   // {a00,a01,a10,a11}
    float e1 = __expf(-c.x);
    float e2 = __expf(-c.w);
    float f  = c.z * e2;
    float P  = e1 * e1 * fmaf(f, f, 1.f);
    float Q  = e2 * e2;
    float R  = -2.f * f * e1 * e2;

    __syncthreads();

    float* st = &stage[p * KK];            // bank stride 25: 2-way, free
#pragma unroll 5
    for (int k = k0; k < k1; ++k) {
        vf4 g = s_uvw[k];                  // broadcast read
        st[k] = fmaf(P, g.x, fmaf(Q, g.y, R * g.z));
    }

    __syncthreads();

    // coalesced staged write-out: 1936 float4, contiguous & 16B-aligned,
    // nontemporal (bypass dirty L2/L3 poison lines)
    const vf4* s4 = (const vf4*)stage;
    vf4* o = out4 + (size_t)blockIdx.x * STAGE_F4;
#pragma unroll
    for (int i = t; i < STAGE_F4; i += 256) {
        __builtin_nontemporal_store(s4[i], &o[i]);
    }
}

extern "C" void kernel_launch(void* const* d_in, const int* in_sizes, int n_in,
                              void* d_out, int out_size, void* d_ws, size_t ws_size,
                              hipStream_t stream) {
    const vf4* chol4 = (const vf4*)d_in[0];   // (512,512,2,2) fp32
    const float* pg  = (const float*)d_in[1]; // (2,121) fp32
    vf4* out4        = (vf4*)d_out;           // (512,512,11,11) fp32

    quad_rank3_nt_kernel<<<NBLK, 256, 0, stream>>>(chol4, pg, out4);
}